// Round 1
// baseline (833.956 us; speedup 1.0000x reference)
//
#include <hip/hip_runtime.h>
#include <math.h>

#define NBIN 4096
#define CAPC 4096
#define KSEL 128
#define HDIM 212
#define DAC  16
#define EPSF 1e-8f

// meta[0] = candidate counter, meta[1] = keyHi threshold
__global__ void k_init(const float* __restrict__ x, float* __restrict__ xn,
                       unsigned* __restrict__ hist, unsigned* __restrict__ meta) {
    int t = threadIdx.x;
    __shared__ float rs;
    if (t < 32) {
        float v = x[t];
        float s = v * v;
        #pragma unroll
        for (int o = 16; o >= 1; o >>= 1) s += __shfl_down(s, o);
        if (t == 0) rs = rsqrtf(s + EPSF);
    }
    __syncthreads();
    if (t < 32) xn[t] = x[t] * rs;
    for (int b = t; b < NBIN; b += blockDim.x) hist[b] = 0u;
    if (t == 0) { meta[0] = 0u; meta[1] = 0u; }
}

// 8 threads per row, one float4 each. Coalesced 256MB read.
__global__ __launch_bounds__(256) void k_cos_hist(
        const float4* __restrict__ obs4, const float* __restrict__ xn,
        float* __restrict__ cosb, unsigned* __restrict__ hist, long total) {
    __shared__ unsigned lhist[NBIN];
    __shared__ float xns[32];
    for (int b = threadIdx.x; b < NBIN; b += blockDim.x) lhist[b] = 0u;
    if (threadIdx.x < 32) xns[threadIdx.x] = xn[threadIdx.x];
    __syncthreads();

    long g = (long)blockIdx.x * blockDim.x + threadIdx.x;   // float4 index
    if (g < total) {
        int r = (int)(g & 7);                               // position within row
        float4 v = obs4[g];
        float dot = v.x * xns[4*r+0] + v.y * xns[4*r+1]
                  + v.z * xns[4*r+2] + v.w * xns[4*r+3];
        float nrm = v.x*v.x + v.y*v.y + v.z*v.z + v.w*v.w;
        #pragma unroll
        for (int o = 1; o < 8; o <<= 1) {
            dot += __shfl_xor(dot, o);
            nrm += __shfl_xor(nrm, o);
        }
        if (r == 0) {
            long row = g >> 3;
            float cd = 1.0f - dot * rsqrtf(nrm + EPSF);
            cosb[row] = cd;
            unsigned u = __float_as_uint(cd);
            unsigned key = (u & 0x80000000u) ? ~u : (u | 0x80000000u);
            atomicAdd(&lhist[key >> 20], 1u);
        }
    }
    __syncthreads();
    for (int b = threadIdx.x; b < NBIN; b += blockDim.x) {
        unsigned c = lhist[b];
        if (c) atomicAdd(&hist[b], c);
    }
}

// Single block: prefix-scan the 4096-bin histogram, find the bin holding the
// K-th smallest element, write exclusive-upper key threshold into meta[1].
__global__ __launch_bounds__(1024) void k_scan(const unsigned* __restrict__ hist,
                                               unsigned* __restrict__ meta, int K) {
    __shared__ unsigned psum[1024];
    int t = threadIdx.x;
    unsigned c[4];
    unsigned local = 0;
    #pragma unroll
    for (int q = 0; q < 4; q++) { c[q] = hist[4*t + q]; local += c[q]; }
    psum[t] = local;
    __syncthreads();
    for (int o = 1; o < 1024; o <<= 1) {
        unsigned v = (t >= o) ? psum[t - o] : 0u;
        __syncthreads();
        psum[t] += v;
        __syncthreads();
    }
    unsigned incl = psum[t];
    unsigned excl = incl - local;
    if (excl < (unsigned)K && (unsigned)K <= incl) {
        unsigned cum = excl;
        int B = 4*t;
        #pragma unroll
        for (int q = 0; q < 4; q++) {
            cum += c[q];
            if (cum >= (unsigned)K) { B = 4*t + q; break; }
        }
        unsigned keyHi = (B >= NBIN - 1) ? 0xFFFFFFFFu : ((unsigned)(B + 1) << 20);
        meta[1] = keyHi;
    }
}

__global__ __launch_bounds__(256) void k_compact(
        const float4* __restrict__ cos4, unsigned* __restrict__ meta,
        float* __restrict__ cval, int* __restrict__ cidx, int n4, int N) {
    unsigned keyHi = meta[1];
    int g = blockIdx.x * blockDim.x + threadIdx.x;
    if (g >= n4) return;
    float4 v = cos4[g];
    float vv[4] = {v.x, v.y, v.z, v.w};
    #pragma unroll
    for (int q = 0; q < 4; q++) {
        int i = g*4 + q;
        if (i < N) {
            unsigned u = __float_as_uint(vv[q]);
            unsigned key = (u & 0x80000000u) ? ~u : (u | 0x80000000u);
            if (key < keyHi) {
                unsigned pos = atomicAdd(&meta[0], 1u);
                if (pos < CAPC) { cval[pos] = vv[q]; cidx[pos] = i; }
            }
        }
    }
}

// Single block: bitonic-sort candidates by (val, idx) ascending -> take first
// 128 -> MLP -> softmax -> weighted sum of gathered actions.
__global__ __launch_bounds__(512) void k_final(
        const float* __restrict__ cval, const int* __restrict__ cidx,
        const unsigned* __restrict__ meta, const float* __restrict__ acs,
        const float* __restrict__ w_in, const float* __restrict__ b_in,
        const float* __restrict__ w2, const float* __restrict__ b2,
        const float* __restrict__ w3, const float* __restrict__ b3,
        const float* __restrict__ w_out, const float* __restrict__ b_out,
        float* __restrict__ out) {
    __shared__ float sv[CAPC];
    __shared__ int   si[CAPC];
    __shared__ float d[KSEL];
    __shared__ int   id[KSEL];
    __shared__ float h1[HDIM], h2[HDIM], h3[HDIM], lg[KSEL];
    __shared__ float rsum;

    int t = threadIdx.x;
    int nt = blockDim.x;
    unsigned M = meta[0];
    if (M > CAPC) M = CAPC;
    unsigned Mp2 = KSEL;
    while (Mp2 < M) Mp2 <<= 1;

    for (unsigned i = t; i < Mp2; i += nt) {
        if (i < M) { sv[i] = cval[i]; si[i] = cidx[i]; }
        else       { sv[i] = INFINITY; si[i] = 0x7FFFFFFF; }
    }
    __syncthreads();

    // bitonic sort ascending by (val, idx)
    for (unsigned ksz = 2; ksz <= Mp2; ksz <<= 1) {
        for (unsigned j = ksz >> 1; j > 0; j >>= 1) {
            for (unsigned i = t; i < Mp2; i += nt) {
                unsigned ix = i ^ j;
                if (ix > i) {
                    bool up = ((i & ksz) == 0);
                    float a = sv[i], b = sv[ix];
                    int ai = si[i], bi = si[ix];
                    bool agtb = (a > b) || (a == b && ai > bi);
                    if (agtb == up) {
                        sv[i] = b; sv[ix] = a;
                        si[i] = bi; si[ix] = ai;
                    }
                }
            }
            __syncthreads();
        }
    }

    if (t < KSEL) { d[t] = sv[t]; id[t] = si[t]; }
    __syncthreads();

    // layer 1: [128] -> [212]
    if (t < HDIM) {
        float s = b_in[t];
        const float* wr = &w_in[t * KSEL];
        for (int j = 0; j < KSEL; j++) s += wr[j] * d[j];
        h1[t] = s > 0.f ? s : 0.f;
    }
    __syncthreads();
    // layer 2: [212] -> [212]
    if (t < HDIM) {
        float s = b2[t];
        const float* wr = &w2[t * HDIM];
        for (int j = 0; j < HDIM; j++) s += wr[j] * h1[j];
        h2[t] = s > 0.f ? s : 0.f;
    }
    __syncthreads();
    // layer 3: [212] -> [212]
    if (t < HDIM) {
        float s = b3[t];
        const float* wr = &w3[t * HDIM];
        for (int j = 0; j < HDIM; j++) s += wr[j] * h2[j];
        h3[t] = s > 0.f ? s : 0.f;
    }
    __syncthreads();
    // output layer: [212] -> [128]
    if (t < KSEL) {
        float s = b_out[t];
        const float* wr = &w_out[t * HDIM];
        for (int j = 0; j < HDIM; j++) s += wr[j] * h3[j];
        lg[t] = s;
    }
    __syncthreads();
    // softmax (serial, tiny)
    if (t == 0) {
        float m = -INFINITY;
        for (int j = 0; j < KSEL; j++) m = fmaxf(m, lg[j]);
        float s = 0.f;
        for (int j = 0; j < KSEL; j++) { float e = __expf(lg[j] - m); lg[j] = e; s += e; }
        rsum = 1.0f / s;
    }
    __syncthreads();
    // weighted action sum -> out[16]
    if (t < DAC) {
        float s = 0.f;
        for (int j = 0; j < KSEL; j++)
            s += lg[j] * rsum * acs[(size_t)id[j] * DAC + t];
        out[t] = s;
    }
}

extern "C" void kernel_launch(void* const* d_in, const int* in_sizes, int n_in,
                              void* d_out, int out_size, void* d_ws, size_t ws_size,
                              hipStream_t stream) {
    const float* obs   = (const float*)d_in[0];
    const float* acs   = (const float*)d_in[1];
    const float* x     = (const float*)d_in[2];
    const float* w_in  = (const float*)d_in[3];
    const float* b_in  = (const float*)d_in[4];
    const float* w2    = (const float*)d_in[5];
    const float* b2    = (const float*)d_in[6];
    const float* w3    = (const float*)d_in[7];
    const float* b3    = (const float*)d_in[8];
    const float* w_out = (const float*)d_in[9];
    const float* b_out = (const float*)d_in[10];
    float* out = (float*)d_out;

    int N = in_sizes[0] / 32;

    char* ws = (char*)d_ws;
    float*    xn   = (float*)ws;                       // 32 floats
    float*    cosb = (float*)(ws + 256);               // N floats
    size_t histOff = 256 + (((size_t)N * 4 + 255) / 256) * 256;
    unsigned* hist = (unsigned*)(ws + histOff);        // 4096 u32
    unsigned* meta = (unsigned*)(ws + histOff + NBIN * 4);  // 2 u32
    float*    cval = (float*)(ws + histOff + NBIN * 4 + 256);
    int*      cidx = (int*)(ws + histOff + NBIN * 4 + 256 + CAPC * 4);

    k_init<<<1, 256, 0, stream>>>(x, xn, hist, meta);

    long total = (long)N * 8;                          // float4s in obs
    int g1 = (int)((total + 255) / 256);
    k_cos_hist<<<g1, 256, 0, stream>>>((const float4*)obs, xn, cosb, hist, total);

    k_scan<<<1, 1024, 0, stream>>>(hist, meta, KSEL);

    int n4 = (N + 3) / 4;
    k_compact<<<(n4 + 255) / 256, 256, 0, stream>>>((const float4*)cosb, meta,
                                                    cval, cidx, n4, N);

    k_final<<<1, 512, 0, stream>>>(cval, cidx, meta, acs, w_in, b_in,
                                   w2, b2, w3, b3, w_out, b_out, out);
}

// Round 2
// 171.863 us; speedup vs baseline: 4.8524x; 4.8524x over previous
//
#include <hip/hip_runtime.h>
#include <math.h>

#define NBIN 4096
#define CAPC 4096
#define KSEL 128
#define HDIM 212
#define DAC  16
#define EPSF 1e-8f

// meta[0] = candidate counter, meta[1] = keyHi threshold
__global__ void k_init(const float* __restrict__ x, float* __restrict__ xn,
                       unsigned* __restrict__ hist, unsigned* __restrict__ meta) {
    int t = threadIdx.x;
    __shared__ float rs;
    if (t < 32) {
        float v = x[t];
        float s = v * v;
        #pragma unroll
        for (int o = 16; o >= 1; o >>= 1) s += __shfl_down(s, o);
        if (t == 0) rs = rsqrtf(s + EPSF);
    }
    __syncthreads();
    if (t < 32) xn[t] = x[t] * rs;
    for (int b = t; b < NBIN; b += blockDim.x) hist[b] = 0u;
    if (t == 0) { meta[0] = 0u; meta[1] = 0u; }
}

// Grid-stride, 2048 blocks. 8 threads per row, one float4 each.
// LDS histogram amortized over ~7800 rows per block.
__global__ __launch_bounds__(256) void k_cos_hist(
        const float4* __restrict__ obs4, const float* __restrict__ xn,
        float* __restrict__ cosb, unsigned* __restrict__ hist, long total) {
    __shared__ unsigned lhist[NBIN];
    __shared__ float xns[32];
    for (int b = threadIdx.x; b < NBIN; b += blockDim.x) lhist[b] = 0u;
    if (threadIdx.x < 32) xns[threadIdx.x] = xn[threadIdx.x];
    __syncthreads();

    const long stride = (long)gridDim.x * blockDim.x;
    long g0 = (long)blockIdx.x * blockDim.x + threadIdx.x;
    const int r = (int)(g0 & 7);   // stride % 8 == 0 -> constant per thread
    const float c0 = xns[4*r+0], c1 = xns[4*r+1], c2 = xns[4*r+2], c3 = xns[4*r+3];

    #define PROC(G) do {                                                        \
        float4 v = obs4[(G)];                                                   \
        float dot = v.x * c0 + v.y * c1 + v.z * c2 + v.w * c3;                  \
        float nrm = v.x*v.x + v.y*v.y + v.z*v.z + v.w*v.w;                      \
        _Pragma("unroll")                                                       \
        for (int o = 1; o < 8; o <<= 1) {                                       \
            dot += __shfl_xor(dot, o);                                          \
            nrm += __shfl_xor(nrm, o);                                          \
        }                                                                       \
        if (r == 0) {                                                           \
            long row = (G) >> 3;                                                \
            float cd = 1.0f - dot * rsqrtf(nrm + EPSF);                         \
            cosb[row] = cd;                                                     \
            unsigned u = __float_as_uint(cd);                                   \
            unsigned key = (u & 0x80000000u) ? ~u : (u | 0x80000000u);          \
            atomicAdd(&lhist[key >> 20], 1u);                                   \
        }                                                                       \
    } while (0)

    long g = g0;
    for (; g + 3*stride < total; g += 4*stride) {
        PROC(g);
        PROC(g + stride);
        PROC(g + 2*stride);
        PROC(g + 3*stride);
    }
    for (; g < total; g += stride) PROC(g);
    #undef PROC

    __syncthreads();
    for (int b = threadIdx.x; b < NBIN; b += blockDim.x) {
        unsigned c = lhist[b];
        if (c) atomicAdd(&hist[b], c);
    }
}

// Single block: prefix-scan the 4096-bin histogram, find the bin holding the
// K-th smallest element, write exclusive-upper key threshold into meta[1].
__global__ __launch_bounds__(1024) void k_scan(const unsigned* __restrict__ hist,
                                               unsigned* __restrict__ meta, int K) {
    __shared__ unsigned psum[1024];
    int t = threadIdx.x;
    unsigned c[4];
    unsigned local = 0;
    #pragma unroll
    for (int q = 0; q < 4; q++) { c[q] = hist[4*t + q]; local += c[q]; }
    psum[t] = local;
    __syncthreads();
    for (int o = 1; o < 1024; o <<= 1) {
        unsigned v = (t >= o) ? psum[t - o] : 0u;
        __syncthreads();
        psum[t] += v;
        __syncthreads();
    }
    unsigned incl = psum[t];
    unsigned excl = incl - local;
    if (excl < (unsigned)K && (unsigned)K <= incl) {
        unsigned cum = excl;
        int B = 4*t;
        #pragma unroll
        for (int q = 0; q < 4; q++) {
            cum += c[q];
            if (cum >= (unsigned)K) { B = 4*t + q; break; }
        }
        unsigned keyHi = (B >= NBIN - 1) ? 0xFFFFFFFFu : ((unsigned)(B + 1) << 20);
        meta[1] = keyHi;
    }
}

__global__ __launch_bounds__(256) void k_compact(
        const float4* __restrict__ cos4, unsigned* __restrict__ meta,
        float* __restrict__ cval, int* __restrict__ cidx, int n4, int N) {
    unsigned keyHi = meta[1];
    int g = blockIdx.x * blockDim.x + threadIdx.x;
    if (g >= n4) return;
    float4 v = cos4[g];
    float vv[4] = {v.x, v.y, v.z, v.w};
    #pragma unroll
    for (int q = 0; q < 4; q++) {
        int i = g*4 + q;
        if (i < N) {
            unsigned u = __float_as_uint(vv[q]);
            unsigned key = (u & 0x80000000u) ? ~u : (u | 0x80000000u);
            if (key < keyHi) {
                unsigned pos = atomicAdd(&meta[0], 1u);
                if (pos < CAPC) { cval[pos] = vv[q]; cidx[pos] = i; }
            }
        }
    }
}

// Single block: bitonic-sort candidates by (val, idx) ascending -> take first
// 128 -> MLP -> softmax -> weighted sum of gathered actions.
__global__ __launch_bounds__(512) void k_final(
        const float* __restrict__ cval, const int* __restrict__ cidx,
        const unsigned* __restrict__ meta, const float* __restrict__ acs,
        const float* __restrict__ w_in, const float* __restrict__ b_in,
        const float* __restrict__ w2, const float* __restrict__ b2,
        const float* __restrict__ w3, const float* __restrict__ b3,
        const float* __restrict__ w_out, const float* __restrict__ b_out,
        float* __restrict__ out) {
    __shared__ float sv[CAPC];
    __shared__ int   si[CAPC];
    __shared__ float d[KSEL];
    __shared__ int   id[KSEL];
    __shared__ float h1[HDIM], h2[HDIM], h3[HDIM], lg[KSEL];
    __shared__ float rsum;

    int t = threadIdx.x;
    int nt = blockDim.x;
    unsigned M = meta[0];
    if (M > CAPC) M = CAPC;
    unsigned Mp2 = KSEL;
    while (Mp2 < M) Mp2 <<= 1;

    for (unsigned i = t; i < Mp2; i += nt) {
        if (i < M) { sv[i] = cval[i]; si[i] = cidx[i]; }
        else       { sv[i] = INFINITY; si[i] = 0x7FFFFFFF; }
    }
    __syncthreads();

    // bitonic sort ascending by (val, idx)
    for (unsigned ksz = 2; ksz <= Mp2; ksz <<= 1) {
        for (unsigned j = ksz >> 1; j > 0; j >>= 1) {
            for (unsigned i = t; i < Mp2; i += nt) {
                unsigned ix = i ^ j;
                if (ix > i) {
                    bool up = ((i & ksz) == 0);
                    float a = sv[i], b = sv[ix];
                    int ai = si[i], bi = si[ix];
                    bool agtb = (a > b) || (a == b && ai > bi);
                    if (agtb == up) {
                        sv[i] = b; sv[ix] = a;
                        si[i] = bi; si[ix] = ai;
                    }
                }
            }
            __syncthreads();
        }
    }

    if (t < KSEL) { d[t] = sv[t]; id[t] = si[t]; }
    __syncthreads();

    // layer 1: [128] -> [212]
    if (t < HDIM) {
        float s = b_in[t];
        const float* wr = &w_in[t * KSEL];
        for (int j = 0; j < KSEL; j++) s += wr[j] * d[j];
        h1[t] = s > 0.f ? s : 0.f;
    }
    __syncthreads();
    // layer 2: [212] -> [212]
    if (t < HDIM) {
        float s = b2[t];
        const float* wr = &w2[t * HDIM];
        for (int j = 0; j < HDIM; j++) s += wr[j] * h1[j];
        h2[t] = s > 0.f ? s : 0.f;
    }
    __syncthreads();
    // layer 3: [212] -> [212]
    if (t < HDIM) {
        float s = b3[t];
        const float* wr = &w3[t * HDIM];
        for (int j = 0; j < HDIM; j++) s += wr[j] * h2[j];
        h3[t] = s > 0.f ? s : 0.f;
    }
    __syncthreads();
    // output layer: [212] -> [128]
    if (t < KSEL) {
        float s = b_out[t];
        const float* wr = &w_out[t * HDIM];
        for (int j = 0; j < HDIM; j++) s += wr[j] * h3[j];
        lg[t] = s;
    }
    __syncthreads();
    // softmax (serial, tiny)
    if (t == 0) {
        float m = -INFINITY;
        for (int j = 0; j < KSEL; j++) m = fmaxf(m, lg[j]);
        float s = 0.f;
        for (int j = 0; j < KSEL; j++) { float e = __expf(lg[j] - m); lg[j] = e; s += e; }
        rsum = 1.0f / s;
    }
    __syncthreads();
    // weighted action sum -> out[16]
    if (t < DAC) {
        float s = 0.f;
        for (int j = 0; j < KSEL; j++)
            s += lg[j] * rsum * acs[(size_t)id[j] * DAC + t];
        out[t] = s;
    }
}

extern "C" void kernel_launch(void* const* d_in, const int* in_sizes, int n_in,
                              void* d_out, int out_size, void* d_ws, size_t ws_size,
                              hipStream_t stream) {
    const float* obs   = (const float*)d_in[0];
    const float* acs   = (const float*)d_in[1];
    const float* x     = (const float*)d_in[2];
    const float* w_in  = (const float*)d_in[3];
    const float* b_in  = (const float*)d_in[4];
    const float* w2    = (const float*)d_in[5];
    const float* b2    = (const float*)d_in[6];
    const float* w3    = (const float*)d_in[7];
    const float* b3    = (const float*)d_in[8];
    const float* w_out = (const float*)d_in[9];
    const float* b_out = (const float*)d_in[10];
    float* out = (float*)d_out;

    int N = in_sizes[0] / 32;

    char* ws = (char*)d_ws;
    float*    xn   = (float*)ws;                       // 32 floats
    float*    cosb = (float*)(ws + 256);               // N floats
    size_t histOff = 256 + (((size_t)N * 4 + 255) / 256) * 256;
    unsigned* hist = (unsigned*)(ws + histOff);        // 4096 u32
    unsigned* meta = (unsigned*)(ws + histOff + NBIN * 4);  // 2 u32
    float*    cval = (float*)(ws + histOff + NBIN * 4 + 256);
    int*      cidx = (int*)(ws + histOff + NBIN * 4 + 256 + CAPC * 4);

    k_init<<<1, 256, 0, stream>>>(x, xn, hist, meta);

    long total = (long)N * 8;                          // float4s in obs
    k_cos_hist<<<2048, 256, 0, stream>>>((const float4*)obs, xn, cosb, hist, total);

    k_scan<<<1, 1024, 0, stream>>>(hist, meta, KSEL);

    int n4 = (N + 3) / 4;
    k_compact<<<(n4 + 255) / 256, 256, 0, stream>>>((const float4*)cosb, meta,
                                                    cval, cidx, n4, N);

    k_final<<<1, 512, 0, stream>>>(cval, cidx, meta, acs, w_in, b_in,
                                   w2, b2, w3, b3, w_out, b_out, out);
}